// Round 3
// baseline (1099.792 us; speedup 1.0000x reference)
//
#include <hip/hip_runtime.h>

#define LVL 8
#define C 8192
#define D 128
#define P 8
#define F 4
#define K 4
#define S 4
#define NF 16384
#define NTOT (LVL*C)   // 65536

typedef __bf16 bf16;
typedef bf16 bf16x4 __attribute__((ext_vector_type(4)));
typedef bf16 bf16x8 __attribute__((ext_vector_type(8)));
typedef float f32x4 __attribute__((ext_vector_type(4)));

__device__ __forceinline__ f32x4 mfma16(bf16x8 a, bf16x8 b, f32x4 c) {
  return __builtin_amdgcn_mfma_f32_16x16x32_bf16(a, b, c, 0, 0, 0);
}
__device__ __forceinline__ bf16x4 b4(f32x4 v) {
  bf16x4 r; r[0]=(bf16)v[0]; r[1]=(bf16)v[1]; r[2]=(bf16)v[2]; r[3]=(bf16)v[3]; return r;
}
__device__ __forceinline__ float sigm(float x) { return __builtin_amdgcn_rcpf(1.f + __expf(-x)); }
__device__ __forceinline__ float tanh_(float x) { return 1.f - 2.f*__builtin_amdgcn_rcpf(1.f + __expf(2.f*x)); }

// ---- dtype-flexible accessors (f=1: float32 storage, f=0: bf16 storage) ----
__device__ __forceinline__ float ldf(const void* b, long i, int f) {
  return f ? ((const float*)b)[i] : (float)((const bf16*)b)[i];
}
__device__ __forceinline__ bf16x8 ldx8(const void* b, long i, int f) {
  if (f) {
    f32x4 a = *(const f32x4*)((const float*)b + i);
    f32x4 c = *(const f32x4*)((const float*)b + i + 4);
    bf16x8 r;
    r[0]=(bf16)a[0]; r[1]=(bf16)a[1]; r[2]=(bf16)a[2]; r[3]=(bf16)a[3];
    r[4]=(bf16)c[0]; r[5]=(bf16)c[1]; r[6]=(bf16)c[2]; r[7]=(bf16)c[3];
    return r;
  }
  return *(const bf16x8*)((const bf16*)b + i);
}
__device__ __forceinline__ f32x4 ld4f(const void* b, long i, int f) {
  if (f) return *(const f32x4*)((const float*)b + i);
  bf16x4 t = *(const bf16x4*)((const bf16*)b + i);
  f32x4 r; r[0]=(float)t[0]; r[1]=(float)t[1]; r[2]=(float)t[2]; r[3]=(float)t[3]; return r;
}
__device__ __forceinline__ void st4(void* b, long i, int f, f32x4 v) {
  if (f) *(f32x4*)((float*)b + i) = v;
  else   *(bf16x4*)((bf16*)b + i) = b4(v);
}

// ---------------------------------------------------------------------------
// Scan descriptor: x row source per step t for sequence s:
//   row = idx[t] ? idx[t][s*istride+ioff] : s*istride+ioff
//   element offset = ebase[t] + row*128
// ---------------------------------------------------------------------------
struct SDesc {
  const void* base[13];
  long  ebase[13];
  const int*  idx[13];
  int istride[13];
  int ioff[13];
  int T;
};

// ---------------------------------------------------------------------------
// GRU scan (fused x-projection). 32 seqs/block, 512 thr (8 waves).
// D[gatecol][seq] = Wt x xT + Ut x hT; Wt/Ut persistent in regs; hT/xT LDS dbuf.
// ---------------------------------------------------------------------------
__global__ __launch_bounds__(512, 1) void scan_kernel(SDesc d,
                                                      const bf16* __restrict__ Ut,
                                                      const bf16* __restrict__ Wt,
                                                      const float* __restrict__ bias2,
                                                      void* outbase, long oeb,
                                                      const int* __restrict__ flagp) {
  __shared__ __align__(16) bf16 hT[2][32][136];
  __shared__ __align__(16) bf16 xT[2][32][136];
  const int isf32 = *flagp;
  const int tid = threadIdx.x;
  const int w = tid >> 6;
  const int l15 = tid & 15;
  const int quad = (tid & 63) >> 4;
  const long seq0 = (long)blockIdx.x * 32;

  bf16x8 AU[3][4], AW[3][4];
#pragma unroll
  for (int tr = 0; tr < 3; tr++)
#pragma unroll
    for (int kt = 0; kt < 4; kt++) {
      size_t o = (size_t)(tr*128 + w*16 + l15)*128 + kt*32 + quad*8;
      AU[tr][kt] = *(const bf16x8*)&Ut[o];
      AW[tr][kt] = *(const bf16x8*)&Wt[o];
    }

  const int gc = w*16 + quad*4;
  f32x4 zb  = *(const f32x4*)&bias2[0*128 + gc];
  f32x4 rb  = *(const f32x4*)&bias2[1*128 + gc];
  f32x4 nbx = *(const f32x4*)&bias2[2*128 + gc];
  f32x4 nbh = *(const f32x4*)&bias2[3*128 + gc];

  f32x4 h[2];
#pragma unroll
  for (int nt = 0; nt < 2; nt++) { h[nt][0]=0.f; h[nt][1]=0.f; h[nt][2]=0.f; h[nt][3]=0.f; }

  { int* zp = (int*)&hT[0][0][0];
    for (int i = tid; i < 32*136/2; i += 512) zp[i] = 0; }

  const int prow = tid >> 4;
  const int pc8 = (tid & 15) * 8;

  auto xoff = [&](int t) -> long {
    const int* ip = d.idx[t];
    long s = seq0 + prow;
    long row = ip ? (long)ip[s*d.istride[t] + d.ioff[t]] : s*(long)d.istride[t] + d.ioff[t];
    return d.ebase[t] + row*128 + pc8;
  };

  { bf16x8 x0 = ldx8(d.base[0], xoff(0), isf32); *(bf16x8*)&xT[0][prow][pc8] = x0; }
  __syncthreads();

  int buf = 0;
  for (int t = 0; t < d.T; t++) {
    bf16x8 xnext;
    if (t + 1 < d.T) xnext = ldx8(d.base[t+1], xoff(t+1), isf32);

    f32x4 aZ[2], aR[2], aNx[2], aNh[2];
#pragma unroll
    for (int nt = 0; nt < 2; nt++) { aZ[nt]=zb; aR[nt]=rb; aNx[nt]=nbx; aNh[nt]=nbh; }

    const int xb = t & 1;
#pragma unroll
    for (int kt = 0; kt < 4; kt++) {
      bf16x8 Bh[2], Bx[2];
#pragma unroll
      for (int nt = 0; nt < 2; nt++) {
        Bh[nt] = *(const bf16x8*)&hT[buf][nt*16 + l15][kt*32 + quad*8];
        Bx[nt] = *(const bf16x8*)&xT[xb][nt*16 + l15][kt*32 + quad*8];
      }
#pragma unroll
      for (int nt = 0; nt < 2; nt++) {
        aZ[nt]  = mfma16(AU[0][kt], Bh[nt], aZ[nt]);
        aZ[nt]  = mfma16(AW[0][kt], Bx[nt], aZ[nt]);
        aR[nt]  = mfma16(AU[1][kt], Bh[nt], aR[nt]);
        aR[nt]  = mfma16(AW[1][kt], Bx[nt], aR[nt]);
        aNh[nt] = mfma16(AU[2][kt], Bh[nt], aNh[nt]);
        aNx[nt] = mfma16(AW[2][kt], Bx[nt], aNx[nt]);
      }
    }

#pragma unroll
    for (int nt = 0; nt < 2; nt++) {
      f32x4 hn = h[nt];
#pragma unroll
      for (int i = 0; i < 4; i++) {
        float z = sigm(aZ[nt][i]);
        float r = sigm(aR[nt][i]);
        float n = tanh_(aNx[nt][i] + r*aNh[nt][i]);
        hn[i] = z*hn[i] + (1.f - z)*n;
      }
      h[nt] = hn;
      *(bf16x4*)&hT[1-buf][nt*16 + l15][gc] = b4(hn);
    }
    if (t + 1 < d.T) *(bf16x8*)&xT[1-xb][prow][pc8] = xnext;
    __syncthreads();
    buf ^= 1;
  }

#pragma unroll
  for (int nt = 0; nt < 2; nt++)
    st4(outbase, oeb + (seq0 + nt*16 + l15)*128 + gc, isf32, h[nt]);
}

// ---------------------------------------------------------------------------
// fn GRU scan + fused fe epilogue: out = [h | table[ret]] @ W_fn  (K=256)
// ---------------------------------------------------------------------------
__global__ __launch_bounds__(512, 1) void fnfe_kernel(SDesc d,
                                                      const bf16* __restrict__ Ut,
                                                      const bf16* __restrict__ Wt,
                                                      const float* __restrict__ bias2,
                                                      const bf16* __restrict__ wtT,   // [128][256]
                                                      const void* tabbase,            // d_out (table @ ebase 0)
                                                      const int* __restrict__ retIdx,
                                                      void* outbase, long oeb,
                                                      const int* __restrict__ flagp) {
  __shared__ __align__(16) bf16 hT[2][32][136];
  __shared__ __align__(16) bf16 xT[2][32][136];
  const int isf32 = *flagp;
  const int tid = threadIdx.x;
  const int w = tid >> 6;
  const int l15 = tid & 15;
  const int quad = (tid & 63) >> 4;
  const long seq0 = (long)blockIdx.x * 32;

  bf16x8 AU[3][4], AW[3][4];
#pragma unroll
  for (int tr = 0; tr < 3; tr++)
#pragma unroll
    for (int kt = 0; kt < 4; kt++) {
      size_t o = (size_t)(tr*128 + w*16 + l15)*128 + kt*32 + quad*8;
      AU[tr][kt] = *(const bf16x8*)&Ut[o];
      AW[tr][kt] = *(const bf16x8*)&Wt[o];
    }

  const int gc = w*16 + quad*4;
  f32x4 zb  = *(const f32x4*)&bias2[0*128 + gc];
  f32x4 rb  = *(const f32x4*)&bias2[1*128 + gc];
  f32x4 nbx = *(const f32x4*)&bias2[2*128 + gc];
  f32x4 nbh = *(const f32x4*)&bias2[3*128 + gc];

  f32x4 h[2];
#pragma unroll
  for (int nt = 0; nt < 2; nt++) { h[nt][0]=0.f; h[nt][1]=0.f; h[nt][2]=0.f; h[nt][3]=0.f; }

  { int* zp = (int*)&hT[0][0][0];
    for (int i = tid; i < 32*136/2; i += 512) zp[i] = 0; }

  const int prow = tid >> 4;
  const int pc8 = (tid & 15) * 8;

  auto xoff = [&](int t) -> long {
    const int* ip = d.idx[t];
    long s = seq0 + prow;
    long row = ip ? (long)ip[s*d.istride[t] + d.ioff[t]] : s*(long)d.istride[t] + d.ioff[t];
    return d.ebase[t] + row*128 + pc8;
  };

  { bf16x8 x0 = ldx8(d.base[0], xoff(0), isf32); *(bf16x8*)&xT[0][prow][pc8] = x0; }
  __syncthreads();

  int buf = 0;
  for (int t = 0; t < d.T; t++) {
    bf16x8 xnext;
    if (t + 1 < d.T) xnext = ldx8(d.base[t+1], xoff(t+1), isf32);

    f32x4 aZ[2], aR[2], aNx[2], aNh[2];
#pragma unroll
    for (int nt = 0; nt < 2; nt++) { aZ[nt]=zb; aR[nt]=rb; aNx[nt]=nbx; aNh[nt]=nbh; }

    const int xb = t & 1;
#pragma unroll
    for (int kt = 0; kt < 4; kt++) {
      bf16x8 Bh[2], Bx[2];
#pragma unroll
      for (int nt = 0; nt < 2; nt++) {
        Bh[nt] = *(const bf16x8*)&hT[buf][nt*16 + l15][kt*32 + quad*8];
        Bx[nt] = *(const bf16x8*)&xT[xb][nt*16 + l15][kt*32 + quad*8];
      }
#pragma unroll
      for (int nt = 0; nt < 2; nt++) {
        aZ[nt]  = mfma16(AU[0][kt], Bh[nt], aZ[nt]);
        aZ[nt]  = mfma16(AW[0][kt], Bx[nt], aZ[nt]);
        aR[nt]  = mfma16(AU[1][kt], Bh[nt], aR[nt]);
        aR[nt]  = mfma16(AW[1][kt], Bx[nt], aR[nt]);
        aNh[nt] = mfma16(AU[2][kt], Bh[nt], aNh[nt]);
        aNx[nt] = mfma16(AW[2][kt], Bx[nt], aNx[nt]);
      }
    }

#pragma unroll
    for (int nt = 0; nt < 2; nt++) {
      f32x4 hn = h[nt];
#pragma unroll
      for (int i = 0; i < 4; i++) {
        float z = sigm(aZ[nt][i]);
        float r = sigm(aR[nt][i]);
        float n = tanh_(aNx[nt][i] + r*aNh[nt][i]);
        hn[i] = z*hn[i] + (1.f - z)*n;
      }
      h[nt] = hn;
      *(bf16x4*)&hT[1-buf][nt*16 + l15][gc] = b4(hn);
    }
    if (t + 1 < d.T) *(bf16x8*)&xT[1-xb][prow][pc8] = xnext;
    __syncthreads();
    buf ^= 1;
  }
  // final h^T now in hT[buf]

  // stage ret rows (transposed) into xT[0]
  {
    long ridx = (long)retIdx[seq0 + prow];
    bf16x8 rv = ldx8(tabbase, ridx*128 + pc8, isf32);
    *(bf16x8*)&xT[0][prow][pc8] = rv;
  }
  __syncthreads();

  // fe GEMM: D[fecol][seq], A = wtT rows (out cols), B = [hT | retT]
  f32x4 acc[2];
#pragma unroll
  for (int nt = 0; nt < 2; nt++) { acc[nt][0]=0.f; acc[nt][1]=0.f; acc[nt][2]=0.f; acc[nt][3]=0.f; }
#pragma unroll
  for (int kt = 0; kt < 8; kt++) {
    bf16x8 A = *(const bf16x8*)&wtT[(size_t)(w*16 + l15)*256 + kt*32 + quad*8];
#pragma unroll
    for (int nt = 0; nt < 2; nt++) {
      bf16x8 B = (kt < 4) ? *(const bf16x8*)&hT[buf][nt*16 + l15][kt*32 + quad*8]
                          : *(const bf16x8*)&xT[0][nt*16 + l15][(kt-4)*32 + quad*8];
      acc[nt] = mfma16(A, B, acc[nt]);
    }
  }
#pragma unroll
  for (int nt = 0; nt < 2; nt++)
    st4(outbase, oeb + (seq0 + nt*16 + l15)*128 + gc, isf32, acc[nt]);
}

// ---------------------------------------------------------------------------
// dtype detect: bf16-interpret first 128 u16 of basic_emb; any exponent>=128
// (|v|>=2) is impossible for genuine bf16 data here -> storage is float32.
// ---------------------------------------------------------------------------
__global__ void detect_kernel(const void* be, int* flag) {
  if (threadIdx.x == 0 && blockIdx.x == 0) {
    const unsigned short* u = (const unsigned short*)be;
    int f = 0;
    for (int i = 0; i < 128; i++) {
      unsigned e = (u[i] >> 7) & 0xFF;
      if (e >= 128) f = 1;
    }
    *flag = f;
  }
}

__global__ void convert_kernel(const void* pW, const void* pU, const void* mW, const void* mU,
                               const void* sW, const void* sU, const void* W_fn,
                               const void* pb, const void* mb, const void* sb,
                               bf16* pWt, bf16* pUt, bf16* mWt, bf16* mUt,
                               bf16* sWt, bf16* sUt, bf16* wtT,
                               float* b2p, float* b2m, float* b2s,
                               const int* flagp) {
  const int f = *flagp;
  int i = blockIdx.x*256 + threadIdx.x;
  const int TT = 384*128;
  if (i < 6*TT) {
    int which = i / TT, j = i - which*TT;
    int c = j >> 7, k = j & 127;
    const void* src = (which==0)?pW:(which==1)?pU:(which==2)?mW:(which==3)?mU:(which==4)?sW:sU;
    bf16* dst = (which==0)?pWt:(which==1)?pUt:(which==2)?mWt:(which==3)?mUt:(which==4)?sWt:sUt;
    dst[c*128 + k] = (bf16)ldf(src, (long)k*384 + c, f);
    return;
  }
  i -= 6*TT;
  if (i < 128*256) { int c = i >> 8, k = i & 255; wtT[c*256 + k] = (bf16)ldf(W_fn, (long)k*128 + c, f); return; }
  i -= 128*256;
  if (i < 3*512) {
    int which = i >> 9, j = i & 511;
    const void* b = (which==0)?pb:(which==1)?mb:sb;
    float* dst = (which==0)?b2p:(which==1)?b2m:b2s;
    int g = j >> 7, cc = j & 127;
    float v;
    if (g == 0)      v = ldf(b, cc, f)       + ldf(b, 384 + cc, f);
    else if (g == 1) v = ldf(b, 128 + cc, f) + ldf(b, 512 + cc, f);
    else if (g == 2) v = ldf(b, 256 + cc, f);
    else             v = ldf(b, 640 + cc, f);
    dst[j] = v;
  }
}

__global__ void level0_kernel(const int* __restrict__ basic_ids, const void* basic_emb,
                              void* out, const int* __restrict__ flagp) {
  const int f = *flagp;
  int i = blockIdx.x*256 + threadIdx.x;   // < C*32
  int row = i >> 5, c4 = (i & 31) * 4;
  f32x4 v = ld4f(basic_emb, (long)basic_ids[row]*128 + c4, f);
  st4(out, (long)row*128 + c4, f, v);
}

// ---------------------------------------------------------------------------
extern "C" void kernel_launch(void* const* d_in, const int* in_sizes, int n_in,
                              void* d_out, int out_size, void* d_ws, size_t ws_size,
                              hipStream_t stream) {
  const int* basic_ids      = (const int*)d_in[0];
  const int* prop_idx       = (const int*)d_in[1];
  const int* func_param_idx = (const int*)d_in[2];
  const int* func_ret_idx   = (const int*)d_in[3];
  const int* super_idx      = (const int*)d_in[4];
  const int* glob_param_idx = (const int*)d_in[5];
  const int* glob_ret_idx   = (const int*)d_in[6];
  const void* basic_emb     = d_in[7];
  const void* empty_params  = d_in[8];
  const void* empty_members = d_in[9];
  const void* W_fn = d_in[10];
  const void* pW = d_in[11]; const void* pU = d_in[12]; const void* pb = d_in[13];
  const void* mW = d_in[14]; const void* mU = d_in[15]; const void* mb = d_in[16];
  const void* sW = d_in[17]; const void* sU = d_in[18]; const void* sb = d_in[19];

  // d_out element layout: table [NTOT*128] | glob [NF*128] | memfn [7*C*F*128]
  const long GB = (long)NTOT*128;                 // globout base (scratch until final pass)
  const long MB0 = GB + (long)NF*128;             // memfn base
  auto FEB = [&](int l) { return MB0 + (long)(l-1)*C*F*128; };

  char* wp = (char*)d_ws;
  auto carve = [&](size_t bytes) { char* p = wp; wp += (bytes + 255) & ~(size_t)255; return p; };
  int*  flag = (int*)carve(256);
  bf16* pWt = (bf16*)carve(384*128*2);
  bf16* pUt = (bf16*)carve(384*128*2);
  bf16* mWt = (bf16*)carve(384*128*2);
  bf16* mUt = (bf16*)carve(384*128*2);
  bf16* sWt = (bf16*)carve(384*128*2);
  bf16* sUt = (bf16*)carve(384*128*2);
  bf16* wtT = (bf16*)carve(128*256*2);
  float* b2p = (float*)carve(512*4);
  float* b2m = (float*)carve(512*4);
  float* b2s = (float*)carve(512*4);
  // total ~0.66 MB

  detect_kernel<<<1, 64, 0, stream>>>(basic_emb, flag);
  {
    int total = 6*384*128 + 128*256 + 3*512;
    convert_kernel<<<(total + 255)/256, 256, 0, stream>>>(pW, pU, mW, mU, sW, sU, W_fn,
                                                          pb, mb, sb,
                                                          pWt, pUt, mWt, mUt, sWt, sUt, wtT,
                                                          b2p, b2m, b2s, flag);
  }
  level0_kernel<<<(C*32)/256, 256, 0, stream>>>(basic_ids, basic_emb, d_out, flag);

  for (int l = 1; l < LVL; l++) {
    // fn GRU (C*F seqs, T=5) + fused fe -> memfn[l-1]
    {
      SDesc d{};
      d.T = 5;
      d.base[0] = empty_params; d.ebase[0] = 0; d.idx[0] = nullptr; d.istride[0] = 0; d.ioff[0] = 0;
      for (int t = 1; t < 5; t++) {
        d.base[t] = d_out; d.ebase[t] = 0;
        d.idx[t] = func_param_idx + (size_t)(l-1)*C*F*K; d.istride[t] = K; d.ioff[t] = t-1;
      }
      fnfe_kernel<<<(C*F)/32, 512, 0, stream>>>(d, pUt, pWt, b2p, wtT, d_out,
                                                func_ret_idx + (size_t)(l-1)*C*F,
                                                d_out, FEB(l), flag);
    }
    // member GRU (C seqs, T=13) -> glob region scratch
    {
      SDesc d{};
      d.T = 13;
      d.base[0] = empty_members; d.ebase[0] = 0; d.idx[0] = nullptr; d.istride[0] = 0; d.ioff[0] = 0;
      for (int t = 1; t <= 8; t++) {
        d.base[t] = d_out; d.ebase[t] = 0;
        d.idx[t] = prop_idx + (size_t)(l-1)*C*P; d.istride[t] = P; d.ioff[t] = t-1;
      }
      for (int t = 9; t <= 12; t++) {
        d.base[t] = d_out; d.ebase[t] = FEB(l);
        d.idx[t] = nullptr; d.istride[t] = F; d.ioff[t] = t-9;
      }
      scan_kernel<<<C/32, 512, 0, stream>>>(d, mUt, mWt, b2m, d_out, GB, flag);
    }
    // super GRU (C seqs, T=5) -> table level l
    {
      SDesc d{};
      d.T = 5;
      for (int t = 0; t < 4; t++) {
        d.base[t] = d_out; d.ebase[t] = 0;
        d.idx[t] = super_idx + (size_t)(l-1)*C*S; d.istride[t] = S; d.ioff[t] = t;
      }
      d.base[4] = d_out; d.ebase[4] = GB; d.idx[4] = nullptr; d.istride[4] = 1; d.ioff[4] = 0;
      scan_kernel<<<C/32, 512, 0, stream>>>(d, sUt, sWt, b2s, d_out, (long)l*C*128, flag);
    }
  }

  // global functions (NF seqs, T=5) + fused fe -> glob final
  {
    SDesc d{};
    d.T = 5;
    d.base[0] = empty_params; d.ebase[0] = 0; d.idx[0] = nullptr; d.istride[0] = 0; d.ioff[0] = 0;
    for (int t = 1; t < 5; t++) {
      d.base[t] = d_out; d.ebase[t] = 0;
      d.idx[t] = glob_param_idx; d.istride[t] = K; d.ioff[t] = t-1;
    }
    fnfe_kernel<<<NF/32, 512, 0, stream>>>(d, pUt, pWt, b2p, wtT, d_out,
                                           glob_ret_idx, d_out, GB, flag);
  }
}